// Round 11
// baseline (79.796 us; speedup 1.0000x reference)
//
#include <hip/hip_runtime.h>
#include <math.h>

#define NB 8
#define NH 3
#define NBH 24
#define NP 4096
#define BLK 512              // 8 waves: 4 row-groups x 2 column-halves
#define RPB 128              // rows per block
#define ROWBLKS (NP / RPB)   // 32
#define NPART (ROWBLKS * NBH) // 768 partials in d_ws

typedef _Float16 half4 __attribute__((ext_vector_type(4)));
typedef _Float16 half8 __attribute__((ext_vector_type(8)));
typedef float floatx16 __attribute__((ext_vector_type(16)));

// Forced v_min3_f32 (3-input min; no -ffast-math so compiler won't fuse).
#define MIN3(r, a, b) asm("v_min3_f32 %0, %0, %1, %2" : "+v"(r) : "v"(a), "v"(b))

// MFMA with C = inline constant 0 (verified HW-correct r5-r9, absmax 0.0).
// rsq[row] is constant along the min axis: min_c(rsq+part)=rsq+min_c(part);
// rsq added once after the cross-half combine, before the clamp.
#define MFMA16Z(d, a, bb) \
    asm("v_mfma_f32_32x32x16_f16 %0, %1, %2, 0" : "=&v"(d) : "v"(a), "v"(bb))

// SYMMETRY: reflection is an affine isometric involution => the distance
// matrix is symmetric => cham_x == cham_y; row-mins once, doubled.
//
// v11 = v10's occupancy experiment RERUN WITHOUT SPILL. v10 FAILED
// (absmax 6.0 steady / 468 intermittent): (512,6) caps VGPR at 84 but
// the 2-d-pair core needs ~72 (r0 counter) + 512-thread staging ranges
// => spill around the 16-reg inline-asm MFMA tuples. Session-wide
// correlation: spill near those tuples <=> absmax nonzero (r2/r3: 2.0;
// clean r5-r9: 0.0). Fix: the 1-D-PAIR core, counter-verified at 60
// VGPR (r5) => ~24 regs of slack under the 84 cap. Its exposed
// MFMA->min3 latency (r4 lesson) is precisely what 6 waves/SIMD of TLP
// (vs 3 in every prior design) is meant to cover — ILP traded for TLP.
// Shape: grid (32,24)=768 x 8-wave blocks = 3 blocks/CU, single
// generation, 24 of 32 waves/CU. Waves (rw,ch): rw=wave&3 row group,
// ch=wave>>2 column half (32 stiles, r4's proven loop + U0 offset).
// Col-halves min-combine via 1KB LDS rowmin (r6-passing structure).
// Staging in-block w/ hoisted A-loads (r8); partials+finalize, no
// atomics (r7); finalize sums in double (insurance: closer to the
// exact sum both refs approximate).
__global__ void __launch_bounds__(BLK, 6) chamfer_mfma(const float* __restrict__ pts,
                                                       const float* __restrict__ planes,
                                                       float* __restrict__ partials) {
    __shared__ _Float16 qcols[NP * 4];   // 32 KB: per col [-2c0,-2c1,-2c2,csq]
    __shared__ float rsqbuf[RPB];        // 512 B
    __shared__ float rowmin[2][RPB];     // 1 KB
    __shared__ float bsum[2];

    const int tid  = threadIdx.x;
    const int lane = tid & 63;
    const int wave = tid >> 6;
    const int rw   = wave & 3;   // row group (rows rw*32..rw*32+31)
    const int ch   = wave >> 2;  // column half (stiles ch*32..ch*32+31)
    const int bh   = blockIdx.y;
    const int b    = bh / NH;
    const int h    = lane >> 5;

    const float* pl = planes + bh * 4;
    float n0 = pl[0], n1 = pl[1], n2 = pl[2], off = pl[3];
    float inv = 1.0f / sqrtf(n0 * n0 + n1 * n1 + n2 * n2);
    n0 *= inv; n1 *= inv; n2 *= inv;

    const float* bp = pts + (size_t)b * NP * 3;

    // A-row loads issued FIRST: latency hides under staging.
    const int row = blockIdx.x * RPB + rw * 32 + (lane & 31);
    float a0 = bp[row * 3 + 0], a1 = bp[row * 3 + 1], a2 = bp[row * 3 + 2];

    // stage 4096 reflected cols; one b64 LDS store per column (8 iters)
    #pragma unroll 4
    for (int i = tid; i < NP; i += BLK) {
        float y0 = bp[i * 3 + 0], y1 = bp[i * 3 + 1], y2 = bp[i * 3 + 2];
        float t = 2.0f * (n0 * y0 + n1 * y1 + n2 * y2 + off);
        y0 -= t * n0; y1 -= t * n1; y2 -= t * n2;
        float csq = y0 * y0 + y1 * y1 + y2 * y2;
        half4 q = { (_Float16)(-2.0f * y0), (_Float16)(-2.0f * y1),
                    (_Float16)(-2.0f * y2), (_Float16)csq };
        *(half4*)&qcols[i * 4] = q;
    }

    // A fragments (r5/r8 scheme): lanes<32 carry data in k0-3 (Aev) /
    // k4-7 (Aod); lanes>=32 zero => dup B k8-15 content annihilated.
    float rsqv = a0 * a0 + a1 * a1 + a2 * a2;
    half8 Aev = {0, 0, 0, 0, 0, 0, 0, 0};
    half8 Aod = {0, 0, 0, 0, 0, 0, 0, 0};
    if (lane < 32) {
        Aev[0] = (_Float16)a0; Aev[1] = (_Float16)a1;
        Aev[2] = (_Float16)a2; Aev[3] = (_Float16)1.0f;
        Aod[4] = (_Float16)a0; Aod[5] = (_Float16)a1;
        Aod[6] = (_Float16)a2; Aod[7] = (_Float16)1.0f;
    }
    if (ch == 0 && lane < 32) rsqbuf[rw * 32 + (lane & 31)] = rsqv;
    __syncthreads();   // staging + rsqbuf complete

    float rm[16];
    #pragma unroll
    for (int j = 0; j < 16; ++j) rm[j] = 1e30f;

    // supertile u (64 cols): lane reads cols u*64 + {2l, 2l+1} as one b128.
    // Upper half-wave reads the same address (broadcast, free).
    const _Float16* bcol = &qcols[(lane & 31) * 8];
    const int U0 = ch * 32;
    #define LD(u) (*(const half8*)(bcol + (u) * 256))

    half8 c0 = LD(U0), c1 = LD(U0 + 1), c2 = LD(U0 + 2), c3 = LD(U0 + 3);
    floatx16 dA0, dA1;
    MFMA16Z(dA0, Aev, c0);  MFMA16Z(dA1, Aod, c0);   // st U0

    // r4's proven 1-pair pipeline: consumes st u..u+3, loads u+4..u+7.
    #pragma unroll 1
    for (int u = U0; u < U0 + 28; u += 4) {
        c0 = LD(u + 4);
        #pragma unroll
        for (int j = 0; j < 16; ++j) MIN3(rm[j], dA0[j], dA1[j]);   // st u
        MFMA16Z(dA0, Aev, c1);  MFMA16Z(dA1, Aod, c1);              // st u+1
        c1 = LD(u + 5);
        #pragma unroll
        for (int j = 0; j < 16; ++j) MIN3(rm[j], dA0[j], dA1[j]);   // st u+1
        MFMA16Z(dA0, Aev, c2);  MFMA16Z(dA1, Aod, c2);              // st u+2
        c2 = LD(u + 6);
        #pragma unroll
        for (int j = 0; j < 16; ++j) MIN3(rm[j], dA0[j], dA1[j]);   // st u+2
        MFMA16Z(dA0, Aev, c3);  MFMA16Z(dA1, Aod, c3);              // st u+3
        c3 = LD(u + 7);
        #pragma unroll
        for (int j = 0; j < 16; ++j) MIN3(rm[j], dA0[j], dA1[j]);   // st u+3
        MFMA16Z(dA0, Aev, c0);  MFMA16Z(dA1, Aod, c0);              // st u+4
    }
    {   // epilogue: dA = st U0+28; c1,c2,c3 = stiles U0+29,30,31
        #pragma unroll
        for (int j = 0; j < 16; ++j) MIN3(rm[j], dA0[j], dA1[j]);   // st U0+28
        MFMA16Z(dA0, Aev, c1);  MFMA16Z(dA1, Aod, c1);
        #pragma unroll
        for (int j = 0; j < 16; ++j) MIN3(rm[j], dA0[j], dA1[j]);   // st U0+29
        MFMA16Z(dA0, Aev, c2);  MFMA16Z(dA1, Aod, c2);
        #pragma unroll
        for (int j = 0; j < 16; ++j) MIN3(rm[j], dA0[j], dA1[j]);   // st U0+30
        MFMA16Z(dA0, Aev, c3);  MFMA16Z(dA1, Aod, c3);
        #pragma unroll
        for (int j = 0; j < 16; ++j) MIN3(rm[j], dA0[j], dA1[j]);   // st U0+31
    }
    #undef LD

    // min across the 32 col-slots sharing each row (within this half)
    #pragma unroll
    for (int j = 0; j < 16; ++j) {
        float v = rm[j];
        v = fminf(v, __shfl_xor(v, 1));
        v = fminf(v, __shfl_xor(v, 2));
        v = fminf(v, __shfl_xor(v, 4));
        v = fminf(v, __shfl_xor(v, 8));
        v = fminf(v, __shfl_xor(v, 16));
        rm[j] = v;
    }

    // publish per-row partial mins (constant j indexing; lanes 0 and 32
    // cover D rows (j&3)+8*(j>>2) and +4 respectively)
    if ((lane & 31) == 0) {
        #pragma unroll
        for (int j = 0; j < 16; ++j)
            rowmin[ch][rw * 32 + (j & 3) + 8 * (j >> 2) + 4 * h] = rm[j];
    }
    __syncthreads();

    // combine col-halves, add rsq, clamp, sum 128 rows (waves 0-1), store
    if (tid < RPB) {
        float m = fminf(rowmin[0][tid], rowmin[1][tid]);
        float v = fmaxf(m + rsqbuf[tid], 0.0f);
        #pragma unroll
        for (int o = 32; o; o >>= 1) v += __shfl_down(v, o);
        if ((tid & 63) == 0) bsum[tid >> 6] = v;
    }
    __syncthreads();
    if (tid == 0)
        partials[blockIdx.y * ROWBLKS + blockIdx.x] = bsum[0] + bsum[1];
}

// 1 block: reduce 768 partials (double accumulation — strictly closer to
// the exact sum both references approximate), compute regularizer,
// single store to out. No atomics; no ordering constraint vs worker.
__global__ void __launch_bounds__(256) finalize(const float* __restrict__ planes,
                                                const float* __restrict__ partials,
                                                float* __restrict__ out) {
    __shared__ double acc[4];
    const int tid = threadIdx.x;
    double s = (double)partials[tid] + (double)partials[tid + 256]
             + (double)partials[tid + 512];
    #pragma unroll
    for (int o = 32; o; o >>= 1) s += __shfl_down(s, o);
    if ((tid & 63) == 0) acc[tid >> 6] = s;
    __syncthreads();
    if (tid == 0) {
        double cham = (acc[0] + acc[1] + acc[2] + acc[3])
                      * (2.0 / (double)(NB * NP));
        float reg = 0.0f;
        for (int bb = 0; bb < NB; ++bb) {
            float n[NH][3];
            for (int hh = 0; hh < NH; ++hh) {
                const float* p2 = planes + (bb * NH + hh) * 4;
                float a0 = p2[0], a1 = p2[1], a2 = p2[2];
                float iv = 1.0f / sqrtf(a0 * a0 + a1 * a1 + a2 * a2);
                n[hh][0] = a0 * iv; n[hh][1] = a1 * iv; n[hh][2] = a2 * iv;
            }
            float fro = 0.0f;
            for (int i = 0; i < NH; ++i)
                for (int j = 0; j < NH; ++j) {
                    float d = n[i][0] * n[j][0] + n[i][1] * n[j][1] + n[i][2] * n[j][2]
                              - (i == j ? 1.0f : 0.0f);
                    fro += d * d;
                }
            reg += 25.0f * sqrtf(fro);
        }
        out[0] = (float)cham + reg;
    }
}

extern "C" void kernel_launch(void* const* d_in, const int* in_sizes, int n_in,
                              void* d_out, int out_size, void* d_ws, size_t ws_size,
                              hipStream_t stream) {
    const float* planes = (const float*)d_in[0];  // (8,3,4) fp32
    const float* pts    = (const float*)d_in[1];  // (8,4096,3) fp32
    float* out          = (float*)d_out;
    float* partials     = (float*)d_ws;           // 768 floats

    dim3 grid(ROWBLKS, NBH);
    chamfer_mfma<<<grid, BLK, 0, stream>>>(pts, planes, partials);
    finalize<<<1, 256, 0, stream>>>(planes, partials, out);
}

// Round 12
// 78.162 us; speedup vs baseline: 1.0209x; 1.0209x over previous
//
#include <hip/hip_runtime.h>
#include <math.h>

#define NB 8
#define NH 3
#define NBH 24
#define NP 4096
#define BLK 256
#define RPB 128              // rows per block: 4 waves x 32 rows, each wave all cols
#define ROWBLKS (NP / RPB)   // 32
#define NPART (ROWBLKS * NBH) // 768 partials in d_ws

typedef _Float16 half4 __attribute__((ext_vector_type(4)));
typedef _Float16 half8 __attribute__((ext_vector_type(8)));
typedef float floatx16 __attribute__((ext_vector_type(16)));

// Forced v_min3_f32 (3-input min; no -ffast-math so compiler won't fuse).
#define MIN3(r, a, b) asm("v_min3_f32 %0, %0, %1, %2" : "+v"(r) : "v"(a), "v"(b))

// MFMA with C = inline constant 0 (verified HW-correct r5-r9, absmax 0.0).
#define MFMA16Z(d, a, bb) \
    asm("v_mfma_f32_32x32x16_f16 %0, %1, %2, 0" : "=&v"(d) : "v"(a), "v"(bb))

// FINAL (v12 = r9 verbatim, the session optimum: 77.87us, absmax 0.0).
//
// SYMMETRY: reflection is an affine isometric involution => the distance
// matrix is symmetric => cham_x == cham_y; row-mins once, doubled.
//
// Session conclusions baked in:
//  - full-K B packing: 4 cols per B col-slot (quarter q in k=4q..4q+3),
//    4 complementary A masks; ONE ds_read_b128 per 128-col supertile,
//    zero bank conflicts, K-usage 100%;
//  - MFMA C=0 + rsq in epilogue (saves 16-reg C operand);
//  - 768 blocks x 4 waves = 3 blocks/CU single generation; (256,3) cap
//    170 >> ~70 live => no spill (cap<live was the r2/r3/r10 disaster:
//    scratch traffic AND absmax corruption around the asm tuples);
//  - no atomics: plain partials + 1-block finalize;
//  - REFUTED levers (do not revisit): L2-streamed B (r4/r5: exposed
//    250-500cyc latency, MfmaUtil 9.6%), 6 waves/SIMD TLP (r11: -2us),
//    ds_read halving beyond this (r9: +0.4us), finer blocks (r5).
//  - Bound: issue/serialization at parked clock (~0.95GHz; DVFS parked
//    by the 41us ws-poison fill). VALU content floor ~10-11us; achieved
//    ~24.4us; harness fixed ~53us.
__global__ void __launch_bounds__(BLK, 3) chamfer_mfma(const float* __restrict__ pts,
                                                       const float* __restrict__ planes,
                                                       float* __restrict__ partials) {
    __shared__ _Float16 qcols[NP * 4];   // 32 KB: per col [-2c0,-2c1,-2c2,csq]
    __shared__ float bsum[4];

    const int tid  = threadIdx.x;
    const int lane = tid & 63;
    const int wave = tid >> 6;
    const int bh   = blockIdx.y;
    const int b    = bh / NH;
    const int h    = lane >> 5;

    const float* pl = planes + bh * 4;
    float n0 = pl[0], n1 = pl[1], n2 = pl[2], off = pl[3];
    float inv = 1.0f / sqrtf(n0 * n0 + n1 * n1 + n2 * n2);
    n0 *= inv; n1 *= inv; n2 *= inv;

    const float* bp = pts + (size_t)b * NP * 3;

    // A-row loads issued FIRST: their latency hides under staging.
    const int row = blockIdx.x * RPB + wave * 32 + (lane & 31);
    float a0 = bp[row * 3 + 0], a1 = bp[row * 3 + 1], a2 = bp[row * 3 + 2];

    // stage 4096 reflected cols; one b64 LDS store per column
    #pragma unroll 4
    for (int i = tid; i < NP; i += BLK) {
        float y0 = bp[i * 3 + 0], y1 = bp[i * 3 + 1], y2 = bp[i * 3 + 2];
        float t = 2.0f * (n0 * y0 + n1 * y1 + n2 * y2 + off);
        y0 -= t * n0; y1 -= t * n1; y2 -= t * n2;
        float csq = y0 * y0 + y1 * y1 + y2 * y2;
        half4 q = { (_Float16)(-2.0f * y0), (_Float16)(-2.0f * y1),
                    (_Float16)(-2.0f * y2), (_Float16)csq };
        *(half4*)&qcols[i * 4] = q;
    }

    // A fragments, 4 quarter-masks. A layout (32x32x16): lanes 0-31 hold
    // k0-7, lanes 32-63 hold k8-15. Each mask is [r0,r1,r2,1] in its
    // 4-k quarter, zero elsewhere — selects one packed column quarter.
    float rsqv = a0 * a0 + a1 * a1 + a2 * a2;
    half8 Aev = {0, 0, 0, 0, 0, 0, 0, 0};   // quarter 0: k0-3  (lanes<32)
    half8 Aod = {0, 0, 0, 0, 0, 0, 0, 0};   // quarter 1: k4-7  (lanes<32)
    half8 Ae2 = {0, 0, 0, 0, 0, 0, 0, 0};   // quarter 2: k8-11 (lanes>=32)
    half8 Ao2 = {0, 0, 0, 0, 0, 0, 0, 0};   // quarter 3: k12-15(lanes>=32)
    if (lane < 32) {
        Aev[0] = (_Float16)a0; Aev[1] = (_Float16)a1;
        Aev[2] = (_Float16)a2; Aev[3] = (_Float16)1.0f;
        Aod[4] = (_Float16)a0; Aod[5] = (_Float16)a1;
        Aod[6] = (_Float16)a2; Aod[7] = (_Float16)1.0f;
    } else {
        Ae2[0] = (_Float16)a0; Ae2[1] = (_Float16)a1;
        Ae2[2] = (_Float16)a2; Ae2[3] = (_Float16)1.0f;
        Ao2[4] = (_Float16)a0; Ao2[5] = (_Float16)a1;
        Ao2[6] = (_Float16)a2; Ao2[7] = (_Float16)1.0f;
    }
    __syncthreads();   // staging complete

    float rm[16];
    #pragma unroll
    for (int j = 0; j < 16; ++j) rm[j] = 1e30f;

    // supertile k = 128 cols. Lane l reads 16B at byte k*1024 +
    // (l&31)*32 + (l>>5)*16: col-slot c=l&31 covers global cols
    // 4c..4c+3; lanes<32 carry cols 4c,4c+1 (k0-7), lanes>=32 carry
    // 4c+2,4c+3 (k8-15). 64 lanes x contiguous 16B = the full 1KB stile.
    const _Float16* bcol = &qcols[(lane & 31) * 16 + (lane >> 5) * 8];
    #define LDS128(k) (*(const half8*)(bcol + (k) * 512))

    half8 c0 = LDS128(0), c1 = LDS128(1), c2 = LDS128(2), c3 = LDS128(3);
    floatx16 dA0, dA1, dB0, dB1;
    MFMA16Z(dA0, Aev, c0);  MFMA16Z(dA1, Aod, c0);   // st0 q01
    MFMA16Z(dB0, Ae2, c0);  MFMA16Z(dB1, Ao2, c0);   // st0 q23

    // Invariant at iter k: c0..c3 = stiles k-4..k-1; dA/dB = stile k-4.
    // Per iter: 4 stiles consumed+issued, 4 loads.
    #pragma unroll 1
    for (int k = 4; k <= 28; k += 4) {
        c0 = LDS128(k);
        #pragma unroll
        for (int j = 0; j < 16; ++j) MIN3(rm[j], dA0[j], dA1[j]);   // st k-4 q01
        MFMA16Z(dA0, Aev, c1);  MFMA16Z(dA1, Aod, c1);              // st k-3 q01
        #pragma unroll
        for (int j = 0; j < 16; ++j) MIN3(rm[j], dB0[j], dB1[j]);   // st k-4 q23
        MFMA16Z(dB0, Ae2, c1);  MFMA16Z(dB1, Ao2, c1);              // st k-3 q23
        c1 = LDS128(k + 1);
        #pragma unroll
        for (int j = 0; j < 16; ++j) MIN3(rm[j], dA0[j], dA1[j]);   // st k-3 q01
        MFMA16Z(dA0, Aev, c2);  MFMA16Z(dA1, Aod, c2);              // st k-2 q01
        #pragma unroll
        for (int j = 0; j < 16; ++j) MIN3(rm[j], dB0[j], dB1[j]);   // st k-3 q23
        MFMA16Z(dB0, Ae2, c2);  MFMA16Z(dB1, Ao2, c2);              // st k-2 q23
        c2 = LDS128(k + 2);
        #pragma unroll
        for (int j = 0; j < 16; ++j) MIN3(rm[j], dA0[j], dA1[j]);   // st k-2 q01
        MFMA16Z(dA0, Aev, c3);  MFMA16Z(dA1, Aod, c3);              // st k-1 q01
        #pragma unroll
        for (int j = 0; j < 16; ++j) MIN3(rm[j], dB0[j], dB1[j]);   // st k-2 q23
        MFMA16Z(dB0, Ae2, c3);  MFMA16Z(dB1, Ao2, c3);              // st k-1 q23
        c3 = LDS128(k + 3);
        #pragma unroll
        for (int j = 0; j < 16; ++j) MIN3(rm[j], dA0[j], dA1[j]);   // st k-1 q01
        MFMA16Z(dA0, Aev, c0);  MFMA16Z(dA1, Aod, c0);              // st k   q01
        #pragma unroll
        for (int j = 0; j < 16; ++j) MIN3(rm[j], dB0[j], dB1[j]);   // st k-1 q23
        MFMA16Z(dB0, Ae2, c0);  MFMA16Z(dB1, Ao2, c0);              // st k   q23
    }
    {   // exit: c0..c3 = st28..31, dA/dB = st28. Drain st28..31.
        #pragma unroll
        for (int j = 0; j < 16; ++j) MIN3(rm[j], dA0[j], dA1[j]);   // st28 q01
        MFMA16Z(dA0, Aev, c1);  MFMA16Z(dA1, Aod, c1);              // st29 q01
        #pragma unroll
        for (int j = 0; j < 16; ++j) MIN3(rm[j], dB0[j], dB1[j]);   // st28 q23
        MFMA16Z(dB0, Ae2, c1);  MFMA16Z(dB1, Ao2, c1);              // st29 q23
        #pragma unroll
        for (int j = 0; j < 16; ++j) MIN3(rm[j], dA0[j], dA1[j]);   // st29 q01
        MFMA16Z(dA0, Aev, c2);  MFMA16Z(dA1, Aod, c2);              // st30 q01
        #pragma unroll
        for (int j = 0; j < 16; ++j) MIN3(rm[j], dB0[j], dB1[j]);   // st29 q23
        MFMA16Z(dB0, Ae2, c2);  MFMA16Z(dB1, Ao2, c2);              // st30 q23
        #pragma unroll
        for (int j = 0; j < 16; ++j) MIN3(rm[j], dA0[j], dA1[j]);   // st30 q01
        MFMA16Z(dA0, Aev, c3);  MFMA16Z(dA1, Aod, c3);              // st31 q01
        #pragma unroll
        for (int j = 0; j < 16; ++j) MIN3(rm[j], dB0[j], dB1[j]);   // st30 q23
        MFMA16Z(dB0, Ae2, c3);  MFMA16Z(dB1, Ao2, c3);              // st31 q23
        #pragma unroll
        for (int j = 0; j < 16; ++j) MIN3(rm[j], dA0[j], dA1[j]);   // st31 q01
        #pragma unroll
        for (int j = 0; j < 16; ++j) MIN3(rm[j], dB0[j], dB1[j]);   // st31 q23
    }
    #undef LDS128

    // min across the 32 col-slots sharing each row — xor-reduce leaves
    // the group min in every lane of the 32-group.
    #pragma unroll
    for (int j = 0; j < 16; ++j) {
        float v = rm[j];
        v = fminf(v, __shfl_xor(v, 1));
        v = fminf(v, __shfl_xor(v, 2));
        v = fminf(v, __shfl_xor(v, 4));
        v = fminf(v, __shfl_xor(v, 8));
        v = fminf(v, __shfl_xor(v, 16));
        rm[j] = v;
    }

    // add rsq (shfl from the lane owning that row), clamp, sum this
    // half-wave's 16 rows (D rows: (j&3)+8*(j>>2)+4*h).
    float s = 0.0f;
    #pragma unroll
    for (int j = 0; j < 16; ++j) {
        float rsqj = __shfl(rsqv, (j & 3) + 8 * (j >> 2) + 4 * h);
        s += fmaxf(rm[j] + rsqj, 0.0f);   // clamp after min: exact
    }
    s += __shfl_xor(s, 32);   // combine the two 16-row halves of the wave

    if (lane == 0) bsum[wave] = s;
    __syncthreads();
    if (tid == 0)
        partials[blockIdx.y * ROWBLKS + blockIdx.x] =
            bsum[0] + bsum[1] + bsum[2] + bsum[3];
}

// 1 block: reduce 768 partials, compute regularizer, single store to out.
// No atomics anywhere; no ordering constraint vs the worker kernel.
__global__ void __launch_bounds__(256) finalize(const float* __restrict__ planes,
                                                const float* __restrict__ partials,
                                                float* __restrict__ out) {
    __shared__ float acc[4];
    const int tid = threadIdx.x;
    float s = partials[tid] + partials[tid + 256] + partials[tid + 512];
    #pragma unroll
    for (int o = 32; o; o >>= 1) s += __shfl_down(s, o);
    if ((tid & 63) == 0) acc[tid >> 6] = s;
    __syncthreads();
    if (tid == 0) {
        float cham = (acc[0] + acc[1] + acc[2] + acc[3]) * (2.0f / (float)(NB * NP));
        float reg = 0.0f;
        for (int bb = 0; bb < NB; ++bb) {
            float n[NH][3];
            for (int hh = 0; hh < NH; ++hh) {
                const float* p2 = planes + (bb * NH + hh) * 4;
                float a0 = p2[0], a1 = p2[1], a2 = p2[2];
                float iv = 1.0f / sqrtf(a0 * a0 + a1 * a1 + a2 * a2);
                n[hh][0] = a0 * iv; n[hh][1] = a1 * iv; n[hh][2] = a2 * iv;
            }
            float fro = 0.0f;
            for (int i = 0; i < NH; ++i)
                for (int j = 0; j < NH; ++j) {
                    float d = n[i][0] * n[j][0] + n[i][1] * n[j][1] + n[i][2] * n[j][2]
                              - (i == j ? 1.0f : 0.0f);
                    fro += d * d;
                }
            reg += 25.0f * sqrtf(fro);
        }
        out[0] = cham + reg;
    }
}

extern "C" void kernel_launch(void* const* d_in, const int* in_sizes, int n_in,
                              void* d_out, int out_size, void* d_ws, size_t ws_size,
                              hipStream_t stream) {
    const float* planes = (const float*)d_in[0];  // (8,3,4) fp32
    const float* pts    = (const float*)d_in[1];  // (8,4096,3) fp32
    float* out          = (float*)d_out;
    float* partials     = (float*)d_ws;           // 768 floats

    dim3 grid(ROWBLKS, NBH);
    chamfer_mfma<<<grid, BLK, 0, stream>>>(pts, planes, partials);
    finalize<<<1, 256, 0, stream>>>(planes, partials, out);
}